// Round 15
// baseline (598.817 us; speedup 1.0000x reference)
//
#include <hip/hip_runtime.h>
#include <hip/hip_bf16.h>

// SetTransEncoder: B=64, N=2048, M=32, D=128, H=4, DH=32, DFF=512, L=2
#define BB 64
#define NN 2048
#define MM 32
#define DD 128
#define HH 4
#define LL 2
#define BN (BB*NN)   // 131072 rows
#define BM (BB*MM)   // 2048 rows

typedef short bf16x8 __attribute__((ext_vector_type(8)));
typedef float f32x4 __attribute__((ext_vector_type(4)));
typedef unsigned int u32;
#define MFMA __builtin_amdgcn_mfma_f32_16x16x32_bf16

// hardware bf16 convert (RNE)
__device__ __forceinline__ unsigned short f2bf(float f){
  __hip_bfloat16 h = __float2bfloat16(f);
  unsigned short u;
  __builtin_memcpy(&u, &h, 2);
  return u;
}
__device__ __forceinline__ float bf2f(unsigned short u){
  union { u32 u; float f; } v; v.u = ((u32)u) << 16; return v.f;
}
__device__ __forceinline__ u32 pack2(float a, float b){
  return (u32)f2bf(a) | ((u32)f2bf(b) << 16);
}
__device__ __forceinline__ float ldf(const float* p){ return *p; }
__device__ __forceinline__ float ldf(const unsigned short* p){ return bf2f(*p); }
__device__ __forceinline__ void stf(float* p, float v){ *p = v; }
__device__ __forceinline__ void stf(unsigned short* p, float v){ *p = f2bf(v); }

__device__ __forceinline__ f32x4 ld4(const float* p){ return *reinterpret_cast<const f32x4*>(p); }
__device__ __forceinline__ f32x4 ld4(const unsigned short* p){
  ushort4 u = *reinterpret_cast<const ushort4*>(p);
  f32x4 r; r[0]=bf2f(u.x); r[1]=bf2f(u.y); r[2]=bf2f(u.z); r[3]=bf2f(u.w); return r;
}
__device__ __forceinline__ void st4(float* p, f32x4 v){ *reinterpret_cast<f32x4*>(p) = v; }
__device__ __forceinline__ void st4(unsigned short* p, f32x4 v){
  ushort4 u; u.x=f2bf(v[0]); u.y=f2bf(v[1]); u.z=f2bf(v[2]); u.w=f2bf(v[3]);
  *reinterpret_cast<ushort4*>(p) = u;
}

__device__ __forceinline__ bf16x8 cvt8(const float* __restrict__ p){
  float4 a = *reinterpret_cast<const float4*>(p);
  float4 b = *reinterpret_cast<const float4*>(p + 4);
  bf16x8 r;
  r[0]=(short)f2bf(a.x); r[1]=(short)f2bf(a.y); r[2]=(short)f2bf(a.z); r[3]=(short)f2bf(a.w);
  r[4]=(short)f2bf(b.x); r[5]=(short)f2bf(b.y); r[6]=(short)f2bf(b.z); r[7]=(short)f2bf(b.w);
  return r;
}

// ---- weight image staging: img holds the EXACT 32KB LDS byte image ----
template<int NW>
__device__ __forceinline__ void stage_img(const unsigned short* __restrict__ img,
                                          unsigned short* Wt){
  int wave = threadIdx.x >> 6, lane = threadIdx.x & 63;
  #pragma unroll
  for (int i = 0; i < 32/NW; i++){
    int off = ((i*NW + wave) << 9);            // 1KB chunks (512 ushorts)
    const unsigned short* gp = img + off + lane*8;
    unsigned short* lp = Wt + off;             // wave-uniform LDS base
    __builtin_amdgcn_global_load_lds(
        (__attribute__((address_space(1))) void*)gp,
        (__attribute__((address_space(3))) void*)lp, 16, 0, 0);
  }
}

__device__ __forceinline__ bf16x8 bfrag(const unsigned short* Wt, int cb, int k0, int lane){
  int c = (cb << 4) + (lane & 15);
  int kk = (k0 + ((lane >> 4) << 3)) ^ ((c & 7) << 3);
  return *reinterpret_cast<const bf16x8*>(Wt + (c << 7) + kk);
}

// A/X-fragment loaders: 32 rows per wave (2 subtiles of 16); [16dim=li][k=lg*8+e]
__device__ __forceinline__ void load_afrag(const float* __restrict__ A, int r0, int lane,
                                           bf16x8 af[2][4]){
  int li = lane & 15, lg = lane >> 4;
  #pragma unroll
  for (int s = 0; s < 2; s++){
    const float* ap = A + (size_t)(r0 + s*16 + li) * 128 + (lg << 3);
    #pragma unroll
    for (int ks = 0; ks < 4; ks++) af[s][ks] = cvt8(ap + ks*32);
  }
}
__device__ __forceinline__ void load_afrag(const unsigned short* __restrict__ A, int r0,
                                           int lane, bf16x8 af[2][4]){
  int li = lane & 15, lg = lane >> 4;
  #pragma unroll
  for (int s = 0; s < 2; s++){
    const unsigned short* ap = A + (size_t)(r0 + s*16 + li) * 128 + (lg << 3);
    #pragma unroll
    for (int ks = 0; ks < 4; ks++) af[s][ks] = *reinterpret_cast<const bf16x8*>(ap + ks*32);
  }
}

// classic order: acc[s][cb][q] = C[row=r0+s*16+lg*4+q][col=cb*16+li]
__device__ __forceinline__ void mfma_tile32(const bf16x8 af[2][4], const unsigned short* Wt,
                                            int lane, f32x4 acc[2][8]){
  #pragma unroll
  for (int ks = 0; ks < 4; ks++){
    #pragma unroll
    for (int cb = 0; cb < 8; cb++){
      bf16x8 b = bfrag(Wt, cb, ks*32, lane);
      acc[0][cb] = MFMA(af[0][ks], b, acc[0][cb], 0, 0, 0);
      acc[1][cb] = MFMA(af[1][ks], b, acc[1][cb], 0, 0, 0);
    }
  }
}
// swapped order: acc[s][cb][q] = C[xrow=s*16+li][wcol=cb*16+lg*4+q]
__device__ __forceinline__ void mfma_swp(const bf16x8 af[2][4], const unsigned short* Wt,
                                         int lane, f32x4 acc[2][8]){
  #pragma unroll
  for (int ks = 0; ks < 4; ks++){
    #pragma unroll
    for (int cb = 0; cb < 8; cb++){
      bf16x8 w = bfrag(Wt, cb, ks*32, lane);
      acc[0][cb] = MFMA(w, af[0][ks], acc[0][cb], 0, 0, 0);
      acc[1][cb] = MFMA(w, af[1][ks], acc[1][cb], 0, 0, 0);
    }
  }
}

__device__ __forceinline__ void zero_acc(f32x4 acc[2][8]){
  #pragma unroll
  for (int s = 0; s < 2; s++)
    #pragma unroll
    for (int cb = 0; cb < 8; cb++) acc[s][cb] = (f32x4){0.f,0.f,0.f,0.f};
}

__device__ __forceinline__ void store_f32(const f32x4 acc[2][8], float* __restrict__ C,
                                          int r0, int lane){
  int li = lane & 15, lg = lane >> 4;
  #pragma unroll
  for (int s = 0; s < 2; s++)
    #pragma unroll
    for (int q = 0; q < 4; q++){
      float* crow = C + (size_t)(r0 + s*16 + lg*4 + q) * 128;
      #pragma unroll
      for (int cb = 0; cb < 8; cb++) crow[cb*16 + li] = acc[s][cb][q];
    }
}
__device__ __forceinline__ void store_bf16(const f32x4 acc[2][8], unsigned short* __restrict__ C,
                                           int r0, int lane){
  int li = lane & 15, lg = lane >> 4;
  #pragma unroll
  for (int s = 0; s < 2; s++)
    #pragma unroll
    for (int q = 0; q < 4; q++){
      unsigned short* crow = C + (size_t)(r0 + s*16 + lg*4 + q) * 128;
      #pragma unroll
      for (int cb = 0; cb < 8; cb++) crow[cb*16 + li] = f2bf(acc[s][cb][q]);
    }
}
// transposed store (bf16): St2[(b*128 + col)*2048 + j], ushort4 along j
__device__ __forceinline__ void store_st2(const f32x4 acc[2][8], unsigned short* __restrict__ St2,
                                          int b, int jb, int lane){
  int li = lane & 15, lg = lane >> 4;
  #pragma unroll
  for (int s = 0; s < 2; s++)
    #pragma unroll
    for (int cb = 0; cb < 8; cb++){
      unsigned short* p = St2 + ((size_t)(b*128 + cb*16 + li))*2048 + jb + s*16 + lg*4;
      st4(p, acc[s][cb]);
    }
}

// classic-layout LN epilogue (used by gemm_ln_f32A only)
template<typename RT, typename OT>
__device__ __forceinline__ void ln_ep(const f32x4 acc[8], const float* __restrict__ bias,
    const RT* __restrict__ resid, unsigned int resmask,
    const float* __restrict__ g, const float* __restrict__ beta,
    OT* __restrict__ C, int r0, int lane){
  int li = lane & 15, lg = lane >> 4;
  float gv[8], bv[8], biasv[8];
  #pragma unroll
  for (int cb = 0; cb < 8; cb++){
    int col = cb*16 + li;
    gv[cb] = g[col]; bv[cb] = beta[col];
    biasv[cb] = bias ? bias[col] : 0.f;
  }
  #pragma unroll
  for (int q = 0; q < 4; q++){
    int r = r0 + lg*4 + q;
    const RT* rrow = resid + (size_t)(r & resmask) * 128;
    float v[8], sum = 0.f, ss = 0.f;
    #pragma unroll
    for (int cb = 0; cb < 8; cb++){
      float x = acc[cb][q] + biasv[cb] + ldf(rrow + cb*16 + li);
      v[cb] = x; sum += x; ss += x*x;
    }
    #pragma unroll
    for (int mk = 1; mk < 16; mk <<= 1){ sum += __shfl_xor(sum, mk); ss += __shfl_xor(ss, mk); }
    float mu = sum * (1.f/128.f);
    float var = ss * (1.f/128.f) - mu*mu;
    float rs = rsqrtf(var + 1e-5f);
    OT* crow = C + (size_t)r * 128;
    #pragma unroll
    for (int cb = 0; cb < 8; cb++)
      stf(crow + cb*16 + li, (v[cb] - mu) * rs * gv[cb] + bv[cb]);
  }
}

// swapped-layout LN: accO[s][cb][q] = OUT[r0+s*16+li][cb*16+lg*4+q]; vectorized.
template<typename RT, typename OT>
__device__ __forceinline__ void ln_swp(const f32x4 accO[2][8], const float* __restrict__ bias,
    const RT* __restrict__ resid, const float* __restrict__ g, const float* __restrict__ beta,
    OT* __restrict__ C, int r0, int lane){
  int li = lane & 15, lg = lane >> 4;
  #pragma unroll
  for (int s = 0; s < 2; s++){
    int r = r0 + s*16 + li;
    const RT* rr = resid + (size_t)r * 128;
    float v[8][4]; float sum = 0.f, ss = 0.f;
    #pragma unroll
    for (int cb = 0; cb < 8; cb++){
      int c0 = cb*16 + lg*4;
      f32x4 rq = ld4(rr + c0);
      f32x4 bq = bias ? *reinterpret_cast<const f32x4*>(bias + c0) : (f32x4){0.f,0.f,0.f,0.f};
      #pragma unroll
      for (int q = 0; q < 4; q++){
        float x = accO[s][cb][q] + bq[q] + rq[q];
        v[cb][q] = x; sum += x; ss += x*x;
      }
    }
    sum += __shfl_xor(sum, 16); ss += __shfl_xor(ss, 16);
    sum += __shfl_xor(sum, 32); ss += __shfl_xor(ss, 32);
    float mu = sum * (1.f/128.f);
    float var = ss * (1.f/128.f) - mu*mu;
    float rs = rsqrtf(var + 1e-5f);
    OT* co = C + (size_t)r * 128;
    #pragma unroll
    for (int cb = 0; cb < 8; cb++){
      int c0 = cb*16 + lg*4;
      f32x4 gq = *reinterpret_cast<const f32x4*>(g + c0);
      f32x4 tq = *reinterpret_cast<const f32x4*>(beta + c0);
      f32x4 o;
      #pragma unroll
      for (int q = 0; q < 4; q++) o[q] = (v[cb][q] - mu) * rs * gq[q] + tq[q];
      st4(co + c0, o);
    }
  }
}

// redistribute swapped-GEMM output (pk[s][cb][w], packed bf16 pairs of
// val[s][cb][q] = M[xrow=s*16+li][d=16cb+4lg+q]) into B-frags M[xrow=li][d=ks*32+lg*8+e].
__device__ __forceinline__ bf16x8 redist(const u32 pk[2][8][2], int s, int ks,
                                         int t, int srcA, int srcB){
  u32 a0 = (u32)__shfl((int)pk[s][2*ks][0],   srcA);
  u32 a1 = (u32)__shfl((int)pk[s][2*ks+1][0], srcA);
  u32 a2 = (u32)__shfl((int)pk[s][2*ks][1],   srcA);
  u32 a3 = (u32)__shfl((int)pk[s][2*ks+1][1], srcA);
  u32 b0 = (u32)__shfl((int)pk[s][2*ks][0],   srcB);
  u32 b1 = (u32)__shfl((int)pk[s][2*ks+1][0], srcB);
  u32 b2 = (u32)__shfl((int)pk[s][2*ks][1],   srcB);
  u32 b3 = (u32)__shfl((int)pk[s][2*ks+1][1], srcB);
  union { u32 u[4]; bf16x8 v; } r;
  r.u[0] = t ? a1 : a0;
  r.u[1] = t ? a3 : a2;
  r.u[2] = t ? b1 : b0;
  r.u[3] = t ? b3 : b2;
  return r.v;
}

// ---------------- kernels ----------------

// fp32 -> bf16 bulk convert (feat -> xb), 8 elements/thread
__global__ __launch_bounds__(256) void cvt_bf16(const float* __restrict__ in,
                                                unsigned short* __restrict__ out){
  size_t i = ((size_t)blockIdx.x*256 + threadIdx.x) * 8;
  float4 a = *reinterpret_cast<const float4*>(in + i);
  float4 b = *reinterpret_cast<const float4*>(in + i + 4);
  ushort4 u0; u0.x=f2bf(a.x); u0.y=f2bf(a.y); u0.z=f2bf(a.z); u0.w=f2bf(a.w);
  ushort4 u1; u1.x=f2bf(b.x); u1.y=f2bf(b.y); u1.z=f2bf(b.z); u1.w=f2bf(b.w);
  *reinterpret_cast<ushort4*>(out + i) = u0;
  *reinterpret_cast<ushort4*>(out + i + 4) = u1;
}

// Convert all standard weights to bf16 swizzled LDS images (48 slots of 16384).
__global__ __launch_bounds__(256) void prep_imgs(const float* __restrict__ Wq,
    const float* __restrict__ Wk, const float* __restrict__ Wv, const float* __restrict__ Wo,
    const float* __restrict__ W1, const float* __restrict__ W2, unsigned short* __restrict__ imgs){
  int slot = blockIdx.x;
  const float* src; int ldw;
  if (slot < 16){
    int j = slot >> 2, m = slot & 3;
    const float* base = (m==0) ? Wq : (m==1) ? Wk : (m==2) ? Wv : Wo;
    src = base + j*16384; ldw = 128;
  } else if (slot < 32){
    int s = slot - 16; int j = s >> 2, dc = s & 3;
    src = W1 + j*65536 + dc*128; ldw = 512;
  } else {
    int s = slot - 32; int j = s >> 2, dc = s & 3;
    src = W2 + j*65536 + dc*16384; ldw = 128;
  }
  unsigned short* img = imgs + (size_t)slot * 16384;
  for (int i = threadIdx.x; i < 16384; i += 256){
    int k = i >> 7, c = i & 127;
    img[(c << 7) + (k ^ ((c & 7) << 3))] = f2bf(src[k*ldw + c]);
  }
}

// Qi = I @ Wq; WfImg[k][c] = bf16(scale * sum_d Wk[k][hc*32+d] * Qi[qc][hc*32+d])
__global__ __launch_bounds__(256) void prep_phaseA(const float* __restrict__ I,
    const float* __restrict__ Wq, const float* __restrict__ Wk, unsigned short* __restrict__ WfImg){
  __shared__ float Qi[32*128];
  for (int i = threadIdx.x; i < 4096; i += 256){
    int q = i >> 7, c = i & 127;
    float s = 0.f;
    #pragma unroll 8
    for (int d = 0; d < 128; d++) s += I[q*128 + d] * Wq[d*128 + c];
    Qi[i] = s;
  }
  __syncthreads();
  const float scale = 0.17677669529663687f; // 1/sqrt(32)
  for (int i = threadIdx.x; i < 1024; i += 256){
    int k = (blockIdx.x << 3) + (i >> 7), c = i & 127;
    int hc = c >> 5, qc = c & 31;
    float s = 0.f;
    #pragma unroll
    for (int d = 0; d < 32; d++) s += Wk[k*128 + hc*32 + d] * Qi[qc*128 + hc*32 + d];
    WfImg[(c << 7) + (k ^ ((c & 7) << 3))] = f2bf(s * scale);
  }
}

// phase-B fold images: grid = BB*8; part owns 16 cols of Wf and 16 of GvWo.
__global__ __launch_bounds__(256) void prep_phaseB(const float* __restrict__ Wq,
    const float* __restrict__ Wo, const float* __restrict__ Khb, const float* __restrict__ Vhb,
    unsigned short* __restrict__ WfImgs, unsigned short* __restrict__ GvImgs){
  __shared__ float Ks[32*129];
  __shared__ float Vs[32*129];
  __shared__ float Wqt[128*33];
  __shared__ float Wot[128*17];
  int b = blockIdx.x >> 3, part = blockIdx.x & 7;
  int hwf = part >> 1;
  for (int i = threadIdx.x; i < 4096; i += 256){
    int k = i >> 7, c = i & 127;
    Ks[k*129 + c] = Khb[b*4096 + i];
    Vs[k*129 + c] = Vhb[b*4096 + i];
  }
  for (int i = threadIdx.x; i < 4096; i += 256){
    int ci = i >> 5, d = i & 31;
    Wqt[ci*33 + d] = Wq[ci*128 + hwf*32 + d];
  }
  for (int i = threadIdx.x; i < 2048; i += 256){
    int row = i >> 4, cl = i & 15;
    Wot[row*17 + cl] = Wo[row*128 + part*16 + cl];
  }
  __syncthreads();
  const float scale = 0.17677669529663687f;
  unsigned short* wf = WfImgs + (size_t)b*16384;
  unsigned short* gv = GvImgs + (size_t)b*16384;
  {
    int ci = threadIdx.x & 127;
    float wq[32];
    #pragma unroll
    for (int d = 0; d < 32; d++) wq[d] = Wqt[ci*33 + d];
    #pragma unroll
    for (int it = 0; it < 8; it++){
      int kp = part*16 + (threadIdx.x >> 7) + it*2;
      int k = kp & 31;
      float s = 0.f;
      #pragma unroll
      for (int d = 0; d < 32; d++) s += wq[d] * Ks[k*129 + hwf*32 + d];
      wf[(kp << 7) + (ci ^ ((kp & 7) << 3))] = f2bf(s * scale);
    }
  }
  {
    int kp = threadIdx.x & 127;
    int h = kp >> 5, k = kp & 31;
    float vv[32];
    #pragma unroll
    for (int d = 0; d < 32; d++) vv[d] = Vs[k*129 + h*32 + d];
    #pragma unroll
    for (int it = 0; it < 8; it++){
      int c = part*16 + (threadIdx.x >> 7) + it*2;
      int cl = c & 15;
      float s = 0.f;
      #pragma unroll
      for (int d = 0; d < 32; d++) s += vv[d] * Wot[(h*32 + d)*17 + cl];
      gv[(c << 7) + (kp ^ ((c & 7) << 3))] = f2bf(s);
    }
  }
}

// dual GEMM (512t, 256 rows): St2 = (X@W0)^T bf16, V = X@W1 bf16.
template<typename TX>
__global__ __launch_bounds__(512) void gemm_dual(const TX* __restrict__ X,
    const unsigned short* __restrict__ img0, const unsigned short* __restrict__ img1,
    unsigned short* __restrict__ St2, unsigned short* __restrict__ Vb){
  __shared__ __align__(16) unsigned short W0[16384];
  __shared__ __align__(16) unsigned short W1s[16384];
  stage_img<8>(img0, W0);
  stage_img<8>(img1, W1s);
  __syncthreads();
  int lane = threadIdx.x & 63, wave = threadIdx.x >> 6;
  int r0 = blockIdx.x*256 + wave*32;
  int b = r0 >> 11, jb = r0 & 2047;
  bf16x8 af[2][4];
  load_afrag(X, r0, lane, af);
  f32x4 acc[2][8];
  zero_acc(acc);
  mfma_tile32(af, W0, lane, acc);
  store_st2(acc, St2, b, jb, lane);
  zero_acc(acc);
  mfma_tile32(af, W1s, lane, acc);
  store_bf16(acc, Vb, r0, lane);
}

// plain GEMM (fp32 A, fp32 out), 256t/128 rows (BM-sized uses)
__global__ __launch_bounds__(256) void gemm_img(const float* __restrict__ A,
    const unsigned short* __restrict__ img, float* __restrict__ C){
  __shared__ __align__(16) unsigned short Wt[16384];
  stage_img<4>(img, Wt);
  __syncthreads();
  int lane = threadIdx.x & 63, wave = threadIdx.x >> 6;
  int r0 = blockIdx.x*128 + wave*32;
  bf16x8 af[2][4];
  load_afrag(A, r0, lane, af);
  f32x4 acc[2][8];
  zero_acc(acc);
  mfma_tile32(af, Wt, lane, acc);
  store_f32(acc, C, r0, lane);
}

// GEMM + LN epilogue, fp32 A, fp32 out (BM path)
__global__ __launch_bounds__(256) void gemm_ln_f32A(const float* __restrict__ A,
    const unsigned short* __restrict__ img, const float* __restrict__ resid, unsigned int resmask,
    const float* __restrict__ g, const float* __restrict__ beta, float* __restrict__ C){
  __shared__ __align__(16) unsigned short Wt[16384];
  stage_img<4>(img, Wt);
  __syncthreads();
  int lane = threadIdx.x & 63, wave = threadIdx.x >> 6;
  int r0 = blockIdx.x*128 + wave*32;
  bf16x8 af[2][4];
  load_afrag(A, r0, lane, af);
  f32x4 acc[2][8];
  zero_acc(acc);
  mfma_tile32(af, Wt, lane, acc);
  ln_ep(acc[0], nullptr, resid, resmask, g, beta, C, r0,      lane);
  ln_ep(acc[1], nullptr, resid, resmask, g, beta, C, r0 + 16, lane);
}

// induced attention via MFMA; St2 bf16.
__global__ __launch_bounds__(512) void attn_pv(const unsigned short* __restrict__ St2,
    const unsigned short* __restrict__ V, float* __restrict__ O){
  __shared__ __align__(16) unsigned short Vt[2][4096];
  __shared__ __align__(16) float Ocomb[4][64][4];
  __shared__ float scomb[4][16];
  int b = blockIdx.x >> 2, h = blockIdx.x & 3;
  int lane = threadIdx.x & 63, w = threadIdx.x >> 6;
  int li = lane & 15, lg = lane >> 4;
  int qh = w & 1, dh = (w >> 1) & 1, jh = w >> 2;
  int tq = w & 3;
  const unsigned short* Sp = St2 + ((size_t)(b*128 + h*32 + qh*16 + li)) * 2048 + jh*1024;
  const unsigned short* Vb = V + (size_t)b*NN*128 + h*32;
  unsigned short* VtJ = Vt[jh];
  int vrow = tq*32 + (lane >> 2);
  int vd0  = (lane & 3) * 8;
  const unsigned short* vsrc = Vb + ((size_t)(jh*1024 + vrow))*128 + vd0;

  f32x4 acc = (f32x4){0.f,0.f,0.f,0.f};
  float s = 0.f;
  bf16x8 Ar[2][4];
  bf16x8 vr[2][2];

  #pragma unroll
  for (int t = 0; t < 2; t++)
    vr[0][t] = *reinterpret_cast<const bf16x8*>(vsrc + (size_t)t*16*128);
  #pragma unroll
  for (int ks = 0; ks < 4; ks++)
    Ar[0][ks] = *reinterpret_cast<const bf16x8*>(Sp + ks*32 + lg*8);

  #pragma unroll
  for (int c = 0; c < 8; c++){
    const int cur = c & 1, nxt = cur ^ 1;
    __syncthreads();
    #pragma unroll
    for (int t = 0; t < 2; t++){
      int jl = vrow + t*16;
      #pragma unroll
      for (int e = 0; e < 8; e++){
        int d = vd0 + e;
        VtJ[(d << 7) + (jl ^ ((d & 7) << 3))] = (unsigned short)vr[cur][t][e];
      }
    }
    __syncthreads();
    if (c < 7){
      #pragma unroll
      for (int t = 0; t < 2; t++)
        vr[nxt][t] = *reinterpret_cast<const bf16x8*>(vsrc + ((size_t)(c+1)*128 + t*16)*128);
      #pragma unroll
      for (int ks = 0; ks < 4; ks++)
        Ar[nxt][ks] = *reinterpret_cast<const bf16x8*>(Sp + (c+1)*128 + ks*32 + lg*8);
    }
    #pragma unroll
    for (int ks = 0; ks < 4; ks++){
      bf16x8 a;
      #pragma unroll
      for (int e = 0; e < 8; e++){
        float pv = __expf(fminf(bf2f((unsigned short)Ar[cur][ks][e]), 60.f));
        s += pv; a[e] = (short)f2bf(pv);
      }
      bf16x8 bb = bfrag(VtJ, dh, ks*32, lane);
      acc = MFMA(a, bb, acc, 0, 0, 0);
    }
  }
  s += __shfl_xor(s, 16);
  s += __shfl_xor(s, 32);
  if (jh == 1){
    *reinterpret_cast<f32x4*>(&Ocomb[tq][lane][0]) = acc;
    if (lg == 0) scomb[tq][li] = s;
  }
  __syncthreads();
  if (jh == 0){
    acc += *reinterpret_cast<const f32x4*>(&Ocomb[tq][lane][0]);
    float inv = 1.f / (s + scomb[tq][li]);
    float* op = O + ((size_t)(b*MM + qh*16))*128 + h*32 + dh*16 + li;
    #pragma unroll
    for (int r = 0; r < 4; r++){
      float iv = __shfl(inv, lg*4 + r);
      op[(size_t)(lg*4 + r)*128] = acc[r] * iv;
    }
  }
}

// fused FFN, operand-swapped (BM path); 512t / 256 rows / 64KB LDS.
template<typename TA, typename TO>
__global__ __launch_bounds__(512, 2) void ffn_swp(const TA* __restrict__ X,
    const unsigned short* __restrict__ W1i, const float* __restrict__ b1,
    const unsigned short* __restrict__ W2i, const float* __restrict__ b2,
    const float* __restrict__ g, const float* __restrict__ beta,
    TO* __restrict__ OUT){
  __shared__ __align__(16) unsigned short Wt0[16384];
  __shared__ __align__(16) unsigned short Wt1[16384];
  int lane = threadIdx.x & 63, wave = threadIdx.x >> 6;
  int li = lane & 15, lg = lane >> 4;
  int r0 = blockIdx.x*256 + wave*32;
  bf16x8 af[2][4];
  load_afrag(X, r0, lane, af);
  f32x4 accO[2][8];
  zero_acc(accO);
  stage_img<8>(W1i, Wt0);
  stage_img<8>(W2i, Wt1);
  __syncthreads();
  int t = lg >> 1;
  int srcA = li + (((lane >> 4) & 1) << 5);
  int srcB = srcA + 16;
  for (int dc = 0; dc < 4; dc++){
    f32x4 acc1[2][8];
    zero_acc(acc1);
    mfma_swp(af, Wt0, lane, acc1);
    u32 pk[2][8][2];
    #pragma unroll
    for (int s = 0; s < 2; s++)
      #pragma unroll
      for (int cb = 0; cb < 8; cb++){
        f32x4 bq = *reinterpret_cast<const f32x4*>(b1 + dc*128 + cb*16 + lg*4);
        float v0 = fmaxf(acc1[s][cb][0] + bq[0], 0.f);
        float v1 = fmaxf(acc1[s][cb][1] + bq[1], 0.f);
        float v2 = fmaxf(acc1[s][cb][2] + bq[2], 0.f);
        float v3 = fmaxf(acc1[s][cb][3] + bq[3], 0.f);
        pk[s][cb][0] = pack2(v0, v1);
        pk[s][cb][1] = pack2(v2, v3);
      }
    __syncthreads();
    if (dc < 3) stage_img<8>(W1i + (dc+1)*16384, Wt0);
    #pragma unroll
    for (int ks = 0; ks < 4; ks++){
      bf16x8 hb0 = redist(pk, 0, ks, t, srcA, srcB);
      bf16x8 hb1 = redist(pk, 1, ks, t, srcA, srcB);
      #pragma unroll
      for (int cb = 0; cb < 8; cb++){
        bf16x8 w = bfrag(Wt1, cb, ks*32, lane);
        accO[0][cb] = MFMA(w, hb0, accO[0][cb], 0, 0, 0);
        accO[1][cb] = MFMA(w, hb1, accO[1][cb], 0, 0, 0);
      }
    }
    __syncthreads();
    if (dc < 3) stage_img<8>(W2i + (dc+1)*16384, Wt1);
  }
  ln_swp(accO, b2, X, g, beta, OUT, r0, lane);
}

// ===== phase-B FULLY FUSED: x -> scores -> softmax -> PV+Wo -> LN1 (regs) -> FFN -> LN2 -> OUT
// x1 never touches HBM. Register footprint ~245 -> needs 256-VGPR budget:
// __launch_bounds__(512, 1) = 1 block/CU = 2 waves/SIMD (R11/R14 calibration: bigger
// min-blocks forces a lower VGPR cap and catastrophic spill).
template<typename TX, typename TO>
__global__ __launch_bounds__(512, 1) void attn_ffn(const TX* __restrict__ X,
    const unsigned short* __restrict__ WfImgs, const unsigned short* __restrict__ GvImgs,
    const float* __restrict__ g1v, const float* __restrict__ be1v,
    const unsigned short* __restrict__ W1i, const float* __restrict__ b1,
    const unsigned short* __restrict__ W2i, const float* __restrict__ b2,
    const float* __restrict__ g2v, const float* __restrict__ be2v,
    TO* __restrict__ OUT){
  __shared__ __align__(16) unsigned short Wt0[16384];
  __shared__ __align__(16) unsigned short Wt1[16384];
  int b = blockIdx.x >> 3;
  stage_img<8>(WfImgs + (size_t)b*16384, Wt0);
  stage_img<8>(GvImgs + (size_t)b*16384, Wt1);
  int lane = threadIdx.x & 63, wave = threadIdx.x >> 6;
  int li = lane & 15, lg = lane >> 4;
  int r0 = blockIdx.x*256 + wave*32;
  int t = lg >> 1;
  int srcA = li + (((lane >> 4) & 1) << 5);
  int srcB = srcA + 16;
  bf16x8 af[2][4];
  load_afrag(X, r0, lane, af);
  __syncthreads();
  // ---- attention: S = x@Wf (swapped) ----
  f32x4 accO[2][8];
  zero_acc(accO);
  mfma_swp(af, Wt0, lane, accO);      // accO = S[row=s*16+li][kp=16cb+4lg+q]
  // softmax per (s, head)
  u32 pkP[2][8][2];
  #pragma unroll
  for (int s = 0; s < 2; s++)
    #pragma unroll
    for (int h = 0; h < 4; h++){
      float p[8];
      #pragma unroll
      for (int q = 0; q < 4; q++){ p[q] = accO[s][2*h][q]; p[4+q] = accO[s][2*h+1][q]; }
      float m = fmaxf(fmaxf(fmaxf(p[0],p[1]),fmaxf(p[2],p[3])),
                      fmaxf(fmaxf(p[4],p[5]),fmaxf(p[6],p[7])));
      m = fmaxf(m, __shfl_xor(m, 16));
      m = fmaxf(m, __shfl_xor(m, 32));
      float sm = 0.f;
      #pragma unroll
      for (int i = 0; i < 8; i++){ p[i] = __expf(p[i] - m); sm += p[i]; }
      sm += __shfl_xor(sm, 16);
      sm += __shfl_xor(sm, 32);
      float inv = 1.f / sm;
      pkP[s][2*h][0]   = pack2(p[0]*inv, p[1]*inv);
      pkP[s][2*h][1]   = pack2(p[2]*inv, p[3]*inv);
      pkP[s][2*h+1][0] = pack2(p[4]*inv, p[5]*inv);
      pkP[s][2*h+1][1] = pack2(p[6]*inv, p[7]*inv);
    }
  // PV + Wo (reads Wt1)
  zero_acc(accO);
  #pragma unroll
  for (int ks = 0; ks < 4; ks++){
    bf16x8 hb0 = redist(pkP, 0, ks, t, srcA, srcB);
    bf16x8 hb1 = redist(pkP, 1, ks, t, srcA, srcB);
    #pragma unroll
    for (int cb = 0; cb < 8; cb++){
      bf16x8 w = bfrag(Wt1, cb, ks*32, lane);
      accO[0][cb] = MFMA(w, hb0, accO[0][cb], 0, 0, 0);
      accO[1][cb] = MFMA(w, hb1, accO[1][cb], 0, 0, 0);
    }
  }
  __syncthreads();                     // all waves done with Wt0/Wt1 (attn weights)
  stage_img<8>(W1i, Wt0);              // overlap FFN weight staging with LN1 compute
  stage_img<8>(W2i, Wt1);
  // ---- LN1 in-register -> pkX1 (bf16 x1, never stored) ----
  u32 pkX1[2][8][2];
  #pragma unroll
  for (int s = 0; s < 2; s++){
    int r = r0 + s*16 + li;
    const TX* rr = X + (size_t)r * 128;
    float v[8][4]; float sum = 0.f, ss = 0.f;
    #pragma unroll
    for (int cb = 0; cb < 8; cb++){
      int c0 = cb*16 + lg*4;
      f32x4 rq = ld4(rr + c0);
      #pragma unroll
      for (int q = 0; q < 4; q++){
        float x = accO[s][cb][q] + rq[q];
        v[cb][q] = x; sum += x; ss += x*x;
      }
    }
    sum += __shfl_xor(sum, 16); ss += __shfl_xor(ss, 16);
    sum += __shfl_xor(sum, 32); ss += __shfl_xor(ss, 32);
    float mu = sum * (1.f/128.f);
    float var = ss * (1.f/128.f) - mu*mu;
    float rs = rsqrtf(var + 1e-5f);
    #pragma unroll
    for (int cb = 0; cb < 8; cb++){
      int c0 = cb*16 + lg*4;
      f32x4 gq = *reinterpret_cast<const f32x4*>(g1v + c0);
      f32x4 tq = *reinterpret_cast<const f32x4*>(be1v + c0);
      float x0 = (v[cb][0] - mu)*rs*gq[0] + tq[0];
      float x1 = (v[cb][1] - mu)*rs*gq[1] + tq[1];
      float x2 = (v[cb][2] - mu)*rs*gq[2] + tq[2];
      float x3 = (v[cb][3] - mu)*rs*gq[3] + tq[3];
      pkX1[s][cb][0] = pack2(x0, x1);
      pkX1[s][cb][1] = pack2(x2, x3);
    }
  }
  // x1 -> FFN A-fragments (in-register redistribution, no LDS)
  bf16x8 af2[2][4];
  #pragma unroll
  for (int s = 0; s < 2; s++)
    #pragma unroll
    for (int ks = 0; ks < 4; ks++)
      af2[s][ks] = redist(pkX1, s, ks, t, srcA, srcB);
  __syncthreads();                     // W1[0]/W2[0] staged
  // ---- FFN ----
  zero_acc(accO);
  for (int dc = 0; dc < 4; dc++){
    f32x4 acc1[2][8];
    zero_acc(acc1);
    mfma_swp(af2, Wt0, lane, acc1);
    u32 pk[2][8][2];
    #pragma unroll
    for (int s = 0; s < 2; s++)
      #pragma unroll
      for (int cb = 0; cb < 8; cb++){
        f32x4 bq = *reinterpret_cast<const f32x4*>(b1 + dc*128 + cb*16 + lg*4);
        float v0 = fmaxf(acc1[s][cb][0] + bq[0], 0.f);
        float v1 = fmaxf(acc1[s][cb][1] + bq[1], 0.f);
        float v2 = fmaxf(acc1[s][cb][2] + bq[2], 0.f);
        float v3 = fmaxf(acc1[s][cb][3] + bq[3], 0.f);
        pk[s][cb][0] = pack2(v0, v1);
        pk[s][cb][1] = pack2(v2, v3);
      }
    __syncthreads();
    if (dc < 3) stage_img<8>(W1i + (dc+1)*16384, Wt0);
    #pragma unroll
    for (int ks = 0; ks < 4; ks++){
      bf16x8 hb0 = redist(pk, 0, ks, t, srcA, srcB);
      bf16x8 hb1 = redist(pk, 1, ks, t, srcA, srcB);
      #pragma unroll
      for (int cb = 0; cb < 8; cb++){
        bf16x8 w = bfrag(Wt1, cb, ks*32, lane);
        accO[0][cb] = MFMA(w, hb0, accO[0][cb], 0, 0, 0);
        accO[1][cb] = MFMA(w, hb1, accO[1][cb], 0, 0, 0);
      }
    }
    __syncthreads();
    if (dc < 3) stage_img<8>(W2i + (dc+1)*16384, Wt1);
  }
  // ---- LN2 with resid = x1 (unpacked from pkX1) ----
  #pragma unroll
  for (int s = 0; s < 2; s++){
    int r = r0 + s*16 + li;
    float v[8][4]; float sum = 0.f, ss = 0.f;
    #pragma unroll
    for (int cb = 0; cb < 8; cb++){
      int c0 = cb*16 + lg*4;
      f32x4 bq = *reinterpret_cast<const f32x4*>(b2 + c0);
      #pragma unroll
      for (int q = 0; q < 4; q++){
        float resid = bf2f((unsigned short)((pkX1[s][cb][q>>1] >> ((q&1)*16)) & 0xFFFFu));
        float x = accO[s][cb][q] + bq[q] + resid;
        v[cb][q] = x; sum += x; ss += x*x;
      }
    }
    sum += __shfl_xor(sum, 16); ss += __shfl_xor(ss, 16);
    sum += __shfl_xor(sum, 32); ss += __shfl_xor(ss, 32);
    float mu = sum * (1.f/128.f);
    float var = ss * (1.f/128.f) - mu*mu;
    float rs = rsqrtf(var + 1e-5f);
    TO* co = OUT + (size_t)r * 128;
    #pragma unroll
    for (int cb = 0; cb < 8; cb++){
      int c0 = cb*16 + lg*4;
      f32x4 gq = *reinterpret_cast<const f32x4*>(g2v + c0);
      f32x4 tq = *reinterpret_cast<const f32x4*>(be2v + c0);
      f32x4 o;
      #pragma unroll
      for (int q = 0; q < 4; q++) o[q] = (v[cb][q] - mu) * rs * gq[q] + tq[q];
      st4(co + c0, o);
    }
  }
}

extern "C" void kernel_launch(void* const* d_in, const int* in_sizes, int n_in,
                              void* d_out, int out_size, void* d_ws, size_t ws_size,
                              hipStream_t stream){
  (void)in_sizes; (void)n_in; (void)out_size;
  const float* feat = (const float*)d_in[0];
  const float* Ipts = (const float*)d_in[1];
  const float* Wq   = (const float*)d_in[2];
  const float* Wk   = (const float*)d_in[3];
  const float* Wv   = (const float*)d_in[4];
  const float* Wo   = (const float*)d_in[5];
  const float* W1   = (const float*)d_in[6];
  const float* b1   = (const float*)d_in[7];
  const float* W2   = (const float*)d_in[8];
  const float* b2   = (const float*)d_in[9];
  const float* g1   = (const float*)d_in[10];
  const float* be1  = (const float*)d_in[11];
  const float* g2   = (const float*)d_in[12];
  const float* be2  = (const float*)d_in[13];
  float* out = (float*)d_out;

  unsigned short* St2  = (unsigned short*)d_ws;        // 32MB bf16 scores(T)
  unsigned short* bigV = St2 + (size_t)BN*128;         // 32MB bf16 V
  float* Oind  = (float*)(bigV + (size_t)BN*128);
  float* x1ind = Oind  + (size_t)BM*128;
  float* Hind  = x1ind + (size_t)BM*128;
  float* Khb   = Hind  + (size_t)BM*128;
  float* Vhb   = Khb   + (size_t)BM*128;
  unsigned short* imgs = (unsigned short*)(Vhb + (size_t)BM*128);

  unsigned short* imgQKVO = imgs;
  unsigned short* imgW1   = imgs + (size_t)16*16384;
  unsigned short* imgW2   = imgs + (size_t)32*16384;
  unsigned short* imgWf   = imgs + (size_t)48*16384;
  unsigned short* wfB     = imgs + (size_t)50*16384;
  unsigned short* gvB     = imgs + (size_t)114*16384;
  unsigned short* xb      = imgs + (size_t)178*16384;  // 32MB bf16 x (optional)
  size_t need = (size_t)((char*)(xb + (size_t)BN*128) - (char*)d_ws);
  bool useXb = (ws_size >= need);

  prep_imgs<<<48, 256, 0, stream>>>(Wq, Wk, Wv, Wo, W1, W2, imgs);
  if (useXb)
    cvt_bf16<<<BN*128/8/256, 256, 0, stream>>>(feat, xb);

  for (int l = 0; l < LL; l++){
    const float* xf = (l == 0) ? feat : out;
    bool xBf = useXb;
    const float* Il = Ipts + l*MM*DD;
    int j0 = l*2, j1 = l*2 + 1;
    // ---- phase A: H = MAB(I, x) ----
    prep_phaseA<<<16, 256, 0, stream>>>(Il, Wq + j0*16384, Wk + j0*16384, imgWf + l*16384);
    if (xBf)
      gemm_dual<unsigned short><<<BN/256, 512, 0, stream>>>(xb, imgWf + l*16384,
          imgQKVO + (j0*4+2)*16384, St2, bigV);
    else
      gemm_dual<float><<<BN/256, 512, 0, stream>>>(xf, imgWf + l*16384,
          imgQKVO + (j0*4+2)*16384, St2, bigV);
    attn_pv<<<BB*HH, 512, 0, stream>>>(St2, bigV, Oind);
    gemm_ln_f32A<<<BM/128, 256, 0, stream>>>(Oind, imgQKVO + (j0*4+3)*16384, Il, 31u,
                                             g1 + j0*128, be1 + j0*128, x1ind);
    ffn_swp<float, float><<<BM/256, 512, 0, stream>>>(x1ind, imgW1 + (size_t)j0*4*16384,
        b1 + j0*512, imgW2 + (size_t)j0*4*16384, b2 + j0*128,
        g2 + j0*128, be2 + j0*128, Hind);
    // ---- phase B: x = MAB(x, H), fully fused attn+FFN ----
    gemm_img<<<BM/128, 256, 0, stream>>>(Hind, imgQKVO + (j1*4+1)*16384, Khb);
    gemm_img<<<BM/128, 256, 0, stream>>>(Hind, imgQKVO + (j1*4+2)*16384, Vhb);
    prep_phaseB<<<BB*8, 256, 0, stream>>>(Wq + j1*16384, Wo + j1*16384, Khb, Vhb, wfB, gvB);
    if (l == 0 && useXb)
      attn_ffn<unsigned short, unsigned short><<<BN/256, 512, 0, stream>>>(xb, wfB, gvB,
          g1 + j1*128, be1 + j1*128, imgW1 + (size_t)j1*4*16384, b1 + j1*512,
          imgW2 + (size_t)j1*4*16384, b2 + j1*128, g2 + j1*128, be2 + j1*128, xb);
    else if (useXb)
      attn_ffn<unsigned short, float><<<BN/256, 512, 0, stream>>>(xb, wfB, gvB,
          g1 + j1*128, be1 + j1*128, imgW1 + (size_t)j1*4*16384, b1 + j1*512,
          imgW2 + (size_t)j1*4*16384, b2 + j1*128, g2 + j1*128, be2 + j1*128, out);
    else
      attn_ffn<float, float><<<BN/256, 512, 0, stream>>>(xf, wfB, gvB,
          g1 + j1*128, be1 + j1*128, imgW1 + (size_t)j1*4*16384, b1 + j1*512,
          imgW2 + (size_t)j1*4*16384, b2 + j1*128, g2 + j1*128, be2 + j1*128, out);
  }
}

// Round 16
// 536.804 us; speedup vs baseline: 1.1155x; 1.1155x over previous
//
#include <hip/hip_runtime.h>
#include <hip/hip_bf16.h>

// SetTransEncoder: B=64, N=2048, M=32, D=128, H=4, DH=32, DFF=512, L=2
#define BB 64
#define NN 2048
#define MM 32
#define DD 128
#define HH 4
#define LL 2
#define BN (BB*NN)   // 131072 rows
#define BM (BB*MM)   // 2048 rows

typedef short bf16x8 __attribute__((ext_vector_type(8)));
typedef float f32x4 __attribute__((ext_vector_type(4)));
typedef unsigned int u32;
#define MFMA __builtin_amdgcn_mfma_f32_16x16x32_bf16

// hardware bf16 convert (RNE)
__device__ __forceinline__ unsigned short f2bf(float f){
  __hip_bfloat16 h = __float2bfloat16(f);
  unsigned short u;
  __builtin_memcpy(&u, &h, 2);
  return u;
}
__device__ __forceinline__ float bf2f(unsigned short u){
  union { u32 u; float f; } v; v.u = ((u32)u) << 16; return v.f;
}
__device__ __forceinline__ u32 pack2(float a, float b){
  return (u32)f2bf(a) | ((u32)f2bf(b) << 16);
}
__device__ __forceinline__ float ldf(const float* p){ return *p; }
__device__ __forceinline__ float ldf(const unsigned short* p){ return bf2f(*p); }
__device__ __forceinline__ void stf(float* p, float v){ *p = v; }
__device__ __forceinline__ void stf(unsigned short* p, float v){ *p = f2bf(v); }

__device__ __forceinline__ f32x4 ld4(const float* p){ return *reinterpret_cast<const f32x4*>(p); }
__device__ __forceinline__ f32x4 ld4(const unsigned short* p){
  ushort4 u = *reinterpret_cast<const ushort4*>(p);
  f32x4 r; r[0]=bf2f(u.x); r[1]=bf2f(u.y); r[2]=bf2f(u.z); r[3]=bf2f(u.w); return r;
}
__device__ __forceinline__ void st4(float* p, f32x4 v){ *reinterpret_cast<f32x4*>(p) = v; }
__device__ __forceinline__ void st4(unsigned short* p, f32x4 v){
  ushort4 u; u.x=f2bf(v[0]); u.y=f2bf(v[1]); u.z=f2bf(v[2]); u.w=f2bf(v[3]);
  *reinterpret_cast<ushort4*>(p) = u;
}

__device__ __forceinline__ bf16x8 cvt8(const float* __restrict__ p){
  float4 a = *reinterpret_cast<const float4*>(p);
  float4 b = *reinterpret_cast<const float4*>(p + 4);
  bf16x8 r;
  r[0]=(short)f2bf(a.x); r[1]=(short)f2bf(a.y); r[2]=(short)f2bf(a.z); r[3]=(short)f2bf(a.w);
  r[4]=(short)f2bf(b.x); r[5]=(short)f2bf(b.y); r[6]=(short)f2bf(b.z); r[7]=(short)f2bf(b.w);
  return r;
}

// ---- weight image staging: img holds the EXACT 32KB LDS byte image ----
template<int NW>
__device__ __forceinline__ void stage_img(const unsigned short* __restrict__ img,
                                          unsigned short* Wt){
  int wave = threadIdx.x >> 6, lane = threadIdx.x & 63;
  #pragma unroll
  for (int i = 0; i < 32/NW; i++){
    int off = ((i*NW + wave) << 9);            // 1KB chunks (512 ushorts)
    const unsigned short* gp = img + off + lane*8;
    unsigned short* lp = Wt + off;             // wave-uniform LDS base
    __builtin_amdgcn_global_load_lds(
        (__attribute__((address_space(1))) void*)gp,
        (__attribute__((address_space(3))) void*)lp, 16, 0, 0);
  }
}

__device__ __forceinline__ bf16x8 bfrag(const unsigned short* Wt, int cb, int k0, int lane){
  int c = (cb << 4) + (lane & 15);
  int kk = (k0 + ((lane >> 4) << 3)) ^ ((c & 7) << 3);
  return *reinterpret_cast<const bf16x8*>(Wt + (c << 7) + kk);
}

// A/X-fragment loaders: 32 rows per wave (2 subtiles of 16); [16dim=li][k=lg*8+e]
__device__ __forceinline__ void load_afrag(const float* __restrict__ A, int r0, int lane,
                                           bf16x8 af[2][4]){
  int li = lane & 15, lg = lane >> 4;
  #pragma unroll
  for (int s = 0; s < 2; s++){
    const float* ap = A + (size_t)(r0 + s*16 + li) * 128 + (lg << 3);
    #pragma unroll
    for (int ks = 0; ks < 4; ks++) af[s][ks] = cvt8(ap + ks*32);
  }
}
__device__ __forceinline__ void load_afrag(const unsigned short* __restrict__ A, int r0,
                                           int lane, bf16x8 af[2][4]){
  int li = lane & 15, lg = lane >> 4;
  #pragma unroll
  for (int s = 0; s < 2; s++){
    const unsigned short* ap = A + (size_t)(r0 + s*16 + li) * 128 + (lg << 3);
    #pragma unroll
    for (int ks = 0; ks < 4; ks++) af[s][ks] = *reinterpret_cast<const bf16x8*>(ap + ks*32);
  }
}

// classic order: acc[s][cb][q] = C[row=r0+s*16+lg*4+q][col=cb*16+li]
__device__ __forceinline__ void mfma_tile32(const bf16x8 af[2][4], const unsigned short* Wt,
                                            int lane, f32x4 acc[2][8]){
  #pragma unroll
  for (int ks = 0; ks < 4; ks++){
    #pragma unroll
    for (int cb = 0; cb < 8; cb++){
      bf16x8 b = bfrag(Wt, cb, ks*32, lane);
      acc[0][cb] = MFMA(af[0][ks], b, acc[0][cb], 0, 0, 0);
      acc[1][cb] = MFMA(af[1][ks], b, acc[1][cb], 0, 0, 0);
    }
  }
}
// swapped order: acc[s][cb][q] = C[xrow=s*16+li][wcol=cb*16+lg*4+q]
__device__ __forceinline__ void mfma_swp(const bf16x8 af[2][4], const unsigned short* Wt,
                                         int lane, f32x4 acc[2][8]){
  #pragma unroll
  for (int ks = 0; ks < 4; ks++){
    #pragma unroll
    for (int cb = 0; cb < 8; cb++){
      bf16x8 w = bfrag(Wt, cb, ks*32, lane);
      acc[0][cb] = MFMA(w, af[0][ks], acc[0][cb], 0, 0, 0);
      acc[1][cb] = MFMA(w, af[1][ks], acc[1][cb], 0, 0, 0);
    }
  }
}

__device__ __forceinline__ void zero_acc(f32x4 acc[2][8]){
  #pragma unroll
  for (int s = 0; s < 2; s++)
    #pragma unroll
    for (int cb = 0; cb < 8; cb++) acc[s][cb] = (f32x4){0.f,0.f,0.f,0.f};
}

__device__ __forceinline__ void store_f32(const f32x4 acc[2][8], float* __restrict__ C,
                                          int r0, int lane){
  int li = lane & 15, lg = lane >> 4;
  #pragma unroll
  for (int s = 0; s < 2; s++)
    #pragma unroll
    for (int q = 0; q < 4; q++){
      float* crow = C + (size_t)(r0 + s*16 + lg*4 + q) * 128;
      #pragma unroll
      for (int cb = 0; cb < 8; cb++) crow[cb*16 + li] = acc[s][cb][q];
    }
}
__device__ __forceinline__ void store_bf16(const f32x4 acc[2][8], unsigned short* __restrict__ C,
                                           int r0, int lane){
  int li = lane & 15, lg = lane >> 4;
  #pragma unroll
  for (int s = 0; s < 2; s++)
    #pragma unroll
    for (int q = 0; q < 4; q++){
      unsigned short* crow = C + (size_t)(r0 + s*16 + lg*4 + q) * 128;
      #pragma unroll
      for (int cb = 0; cb < 8; cb++) crow[cb*16 + li] = f2bf(acc[s][cb][q]);
    }
}
// transposed store (bf16): St2[(b*128 + col)*2048 + j], ushort4 along j
__device__ __forceinline__ void store_st2(const f32x4 acc[2][8], unsigned short* __restrict__ St2,
                                          int b, int jb, int lane){
  int li = lane & 15, lg = lane >> 4;
  #pragma unroll
  for (int s = 0; s < 2; s++)
    #pragma unroll
    for (int cb = 0; cb < 8; cb++){
      unsigned short* p = St2 + ((size_t)(b*128 + cb*16 + li))*2048 + jb + s*16 + lg*4;
      st4(p, acc[s][cb]);
    }
}

// classic-layout LN epilogue (used by gemm_ln_f32A only)
template<typename RT, typename OT>
__device__ __forceinline__ void ln_ep(const f32x4 acc[8], const float* __restrict__ bias,
    const RT* __restrict__ resid, unsigned int resmask,
    const float* __restrict__ g, const float* __restrict__ beta,
    OT* __restrict__ C, int r0, int lane){
  int li = lane & 15, lg = lane >> 4;
  float gv[8], bv[8], biasv[8];
  #pragma unroll
  for (int cb = 0; cb < 8; cb++){
    int col = cb*16 + li;
    gv[cb] = g[col]; bv[cb] = beta[col];
    biasv[cb] = bias ? bias[col] : 0.f;
  }
  #pragma unroll
  for (int q = 0; q < 4; q++){
    int r = r0 + lg*4 + q;
    const RT* rrow = resid + (size_t)(r & resmask) * 128;
    float v[8], sum = 0.f, ss = 0.f;
    #pragma unroll
    for (int cb = 0; cb < 8; cb++){
      float x = acc[cb][q] + biasv[cb] + ldf(rrow + cb*16 + li);
      v[cb] = x; sum += x; ss += x*x;
    }
    #pragma unroll
    for (int mk = 1; mk < 16; mk <<= 1){ sum += __shfl_xor(sum, mk); ss += __shfl_xor(ss, mk); }
    float mu = sum * (1.f/128.f);
    float var = ss * (1.f/128.f) - mu*mu;
    float rs = rsqrtf(var + 1e-5f);
    OT* crow = C + (size_t)r * 128;
    #pragma unroll
    for (int cb = 0; cb < 8; cb++)
      stf(crow + cb*16 + li, (v[cb] - mu) * rs * gv[cb] + bv[cb]);
  }
}

// swapped-layout LN: accO[s][cb][q] = OUT[r0+s*16+li][cb*16+lg*4+q]; vectorized.
template<typename RT, typename OT>
__device__ __forceinline__ void ln_swp(const f32x4 accO[2][8], const float* __restrict__ bias,
    const RT* __restrict__ resid, const float* __restrict__ g, const float* __restrict__ beta,
    OT* __restrict__ C, int r0, int lane){
  int li = lane & 15, lg = lane >> 4;
  #pragma unroll
  for (int s = 0; s < 2; s++){
    int r = r0 + s*16 + li;
    const RT* rr = resid + (size_t)r * 128;
    float v[8][4]; float sum = 0.f, ss = 0.f;
    #pragma unroll
    for (int cb = 0; cb < 8; cb++){
      int c0 = cb*16 + lg*4;
      f32x4 rq = ld4(rr + c0);
      f32x4 bq = bias ? *reinterpret_cast<const f32x4*>(bias + c0) : (f32x4){0.f,0.f,0.f,0.f};
      #pragma unroll
      for (int q = 0; q < 4; q++){
        float x = accO[s][cb][q] + bq[q] + rq[q];
        v[cb][q] = x; sum += x; ss += x*x;
      }
    }
    sum += __shfl_xor(sum, 16); ss += __shfl_xor(ss, 16);
    sum += __shfl_xor(sum, 32); ss += __shfl_xor(ss, 32);
    float mu = sum * (1.f/128.f);
    float var = ss * (1.f/128.f) - mu*mu;
    float rs = rsqrtf(var + 1e-5f);
    OT* co = C + (size_t)r * 128;
    #pragma unroll
    for (int cb = 0; cb < 8; cb++){
      int c0 = cb*16 + lg*4;
      f32x4 gq = *reinterpret_cast<const f32x4*>(g + c0);
      f32x4 tq = *reinterpret_cast<const f32x4*>(beta + c0);
      f32x4 o;
      #pragma unroll
      for (int q = 0; q < 4; q++) o[q] = (v[cb][q] - mu) * rs * gq[q] + tq[q];
      st4(co + c0, o);
    }
  }
}

// redistribute swapped-GEMM output (pk[s][cb][w], packed bf16 pairs of
// val[s][cb][q] = M[xrow=s*16+li][d=16cb+4lg+q]) into B-frags M[xrow=li][d=ks*32+lg*8+e].
__device__ __forceinline__ bf16x8 redist(const u32 pk[2][8][2], int s, int ks,
                                         int t, int srcA, int srcB){
  u32 a0 = (u32)__shfl((int)pk[s][2*ks][0],   srcA);
  u32 a1 = (u32)__shfl((int)pk[s][2*ks+1][0], srcA);
  u32 a2 = (u32)__shfl((int)pk[s][2*ks][1],   srcA);
  u32 a3 = (u32)__shfl((int)pk[s][2*ks+1][1], srcA);
  u32 b0 = (u32)__shfl((int)pk[s][2*ks][0],   srcB);
  u32 b1 = (u32)__shfl((int)pk[s][2*ks+1][0], srcB);
  u32 b2 = (u32)__shfl((int)pk[s][2*ks][1],   srcB);
  u32 b3 = (u32)__shfl((int)pk[s][2*ks+1][1], srcB);
  union { u32 u[4]; bf16x8 v; } r;
  r.u[0] = t ? a1 : a0;
  r.u[1] = t ? a3 : a2;
  r.u[2] = t ? b1 : b0;
  r.u[3] = t ? b3 : b2;
  return r.v;
}

// ---------------- kernels ----------------

// fp32 -> bf16 bulk convert (feat -> xb), 8 elements/thread
__global__ __launch_bounds__(256) void cvt_bf16(const float* __restrict__ in,
                                                unsigned short* __restrict__ out){
  size_t i = ((size_t)blockIdx.x*256 + threadIdx.x) * 8;
  float4 a = *reinterpret_cast<const float4*>(in + i);
  float4 b = *reinterpret_cast<const float4*>(in + i + 4);
  ushort4 u0; u0.x=f2bf(a.x); u0.y=f2bf(a.y); u0.z=f2bf(a.z); u0.w=f2bf(a.w);
  ushort4 u1; u1.x=f2bf(b.x); u1.y=f2bf(b.y); u1.z=f2bf(b.z); u1.w=f2bf(b.w);
  *reinterpret_cast<ushort4*>(out + i) = u0;
  *reinterpret_cast<ushort4*>(out + i + 4) = u1;
}

// Convert all standard weights to bf16 swizzled LDS images (48 slots of 16384).
__global__ __launch_bounds__(256) void prep_imgs(const float* __restrict__ Wq,
    const float* __restrict__ Wk, const float* __restrict__ Wv, const float* __restrict__ Wo,
    const float* __restrict__ W1, const float* __restrict__ W2, unsigned short* __restrict__ imgs){
  int slot = blockIdx.x;
  const float* src; int ldw;
  if (slot < 16){
    int j = slot >> 2, m = slot & 3;
    const float* base = (m==0) ? Wq : (m==1) ? Wk : (m==2) ? Wv : Wo;
    src = base + j*16384; ldw = 128;
  } else if (slot < 32){
    int s = slot - 16; int j = s >> 2, dc = s & 3;
    src = W1 + j*65536 + dc*128; ldw = 512;
  } else {
    int s = slot - 32; int j = s >> 2, dc = s & 3;
    src = W2 + j*65536 + dc*16384; ldw = 128;
  }
  unsigned short* img = imgs + (size_t)slot * 16384;
  for (int i = threadIdx.x; i < 16384; i += 256){
    int k = i >> 7, c = i & 127;
    img[(c << 7) + (k ^ ((c & 7) << 3))] = f2bf(src[k*ldw + c]);
  }
}

// Qi = I @ Wq; WfImg[k][c] = bf16(scale * sum_d Wk[k][hc*32+d] * Qi[qc][hc*32+d])
__global__ __launch_bounds__(256) void prep_phaseA(const float* __restrict__ I,
    const float* __restrict__ Wq, const float* __restrict__ Wk, unsigned short* __restrict__ WfImg){
  __shared__ float Qi[32*128];
  for (int i = threadIdx.x; i < 4096; i += 256){
    int q = i >> 7, c = i & 127;
    float s = 0.f;
    #pragma unroll 8
    for (int d = 0; d < 128; d++) s += I[q*128 + d] * Wq[d*128 + c];
    Qi[i] = s;
  }
  __syncthreads();
  const float scale = 0.17677669529663687f; // 1/sqrt(32)
  for (int i = threadIdx.x; i < 1024; i += 256){
    int k = (blockIdx.x << 3) + (i >> 7), c = i & 127;
    int hc = c >> 5, qc = c & 31;
    float s = 0.f;
    #pragma unroll
    for (int d = 0; d < 32; d++) s += Wk[k*128 + hc*32 + d] * Qi[qc*128 + hc*32 + d];
    WfImg[(c << 7) + (k ^ ((c & 7) << 3))] = f2bf(s * scale);
  }
}

// phase-B fold images: grid = BB*8; part owns 16 cols of Wf and 16 of GvWo.
__global__ __launch_bounds__(256) void prep_phaseB(const float* __restrict__ Wq,
    const float* __restrict__ Wo, const float* __restrict__ Khb, const float* __restrict__ Vhb,
    unsigned short* __restrict__ WfImgs, unsigned short* __restrict__ GvImgs){
  __shared__ float Ks[32*129];
  __shared__ float Vs[32*129];
  __shared__ float Wqt[128*33];
  __shared__ float Wot[128*17];
  int b = blockIdx.x >> 3, part = blockIdx.x & 7;
  int hwf = part >> 1;
  for (int i = threadIdx.x; i < 4096; i += 256){
    int k = i >> 7, c = i & 127;
    Ks[k*129 + c] = Khb[b*4096 + i];
    Vs[k*129 + c] = Vhb[b*4096 + i];
  }
  for (int i = threadIdx.x; i < 4096; i += 256){
    int ci = i >> 5, d = i & 31;
    Wqt[ci*33 + d] = Wq[ci*128 + hwf*32 + d];
  }
  for (int i = threadIdx.x; i < 2048; i += 256){
    int row = i >> 4, cl = i & 15;
    Wot[row*17 + cl] = Wo[row*128 + part*16 + cl];
  }
  __syncthreads();
  const float scale = 0.17677669529663687f;
  unsigned short* wf = WfImgs + (size_t)b*16384;
  unsigned short* gv = GvImgs + (size_t)b*16384;
  {
    int ci = threadIdx.x & 127;
    float wq[32];
    #pragma unroll
    for (int d = 0; d < 32; d++) wq[d] = Wqt[ci*33 + d];
    #pragma unroll
    for (int it = 0; it < 8; it++){
      int kp = part*16 + (threadIdx.x >> 7) + it*2;
      int k = kp & 31;
      float s = 0.f;
      #pragma unroll
      for (int d = 0; d < 32; d++) s += wq[d] * Ks[k*129 + hwf*32 + d];
      wf[(kp << 7) + (ci ^ ((kp & 7) << 3))] = f2bf(s * scale);
    }
  }
  {
    int kp = threadIdx.x & 127;
    int h = kp >> 5, k = kp & 31;
    float vv[32];
    #pragma unroll
    for (int d = 0; d < 32; d++) vv[d] = Vs[k*129 + h*32 + d];
    #pragma unroll
    for (int it = 0; it < 8; it++){
      int c = part*16 + (threadIdx.x >> 7) + it*2;
      int cl = c & 15;
      float s = 0.f;
      #pragma unroll
      for (int d = 0; d < 32; d++) s += vv[d] * Wot[(h*32 + d)*17 + cl];
      gv[(c << 7) + (kp ^ ((c & 7) << 3))] = f2bf(s);
    }
  }
}

// dual GEMM (512t, 256 rows): St2 = (X@W0)^T bf16, V = X@W1 bf16.
template<typename TX>
__global__ __launch_bounds__(512) void gemm_dual(const TX* __restrict__ X,
    const unsigned short* __restrict__ img0, const unsigned short* __restrict__ img1,
    unsigned short* __restrict__ St2, unsigned short* __restrict__ Vb){
  __shared__ __align__(16) unsigned short W0[16384];
  __shared__ __align__(16) unsigned short W1s[16384];
  stage_img<8>(img0, W0);
  stage_img<8>(img1, W1s);
  __syncthreads();
  int lane = threadIdx.x & 63, wave = threadIdx.x >> 6;
  int r0 = blockIdx.x*256 + wave*32;
  int b = r0 >> 11, jb = r0 & 2047;
  bf16x8 af[2][4];
  load_afrag(X, r0, lane, af);
  f32x4 acc[2][8];
  zero_acc(acc);
  mfma_tile32(af, W0, lane, acc);
  store_st2(acc, St2, b, jb, lane);
  zero_acc(acc);
  mfma_tile32(af, W1s, lane, acc);
  store_bf16(acc, Vb, r0, lane);
}

// plain GEMM (fp32 A, fp32 out), 256t/128 rows (BM-sized uses)
__global__ __launch_bounds__(256) void gemm_img(const float* __restrict__ A,
    const unsigned short* __restrict__ img, float* __restrict__ C){
  __shared__ __align__(16) unsigned short Wt[16384];
  stage_img<4>(img, Wt);
  __syncthreads();
  int lane = threadIdx.x & 63, wave = threadIdx.x >> 6;
  int r0 = blockIdx.x*128 + wave*32;
  bf16x8 af[2][4];
  load_afrag(A, r0, lane, af);
  f32x4 acc[2][8];
  zero_acc(acc);
  mfma_tile32(af, Wt, lane, acc);
  store_f32(acc, C, r0, lane);
}

// GEMM + LN epilogue, fp32 A, fp32 out (BM path)
__global__ __launch_bounds__(256) void gemm_ln_f32A(const float* __restrict__ A,
    const unsigned short* __restrict__ img, const float* __restrict__ resid, unsigned int resmask,
    const float* __restrict__ g, const float* __restrict__ beta, float* __restrict__ C){
  __shared__ __align__(16) unsigned short Wt[16384];
  stage_img<4>(img, Wt);
  __syncthreads();
  int lane = threadIdx.x & 63, wave = threadIdx.x >> 6;
  int r0 = blockIdx.x*128 + wave*32;
  bf16x8 af[2][4];
  load_afrag(A, r0, lane, af);
  f32x4 acc[2][8];
  zero_acc(acc);
  mfma_tile32(af, Wt, lane, acc);
  ln_ep(acc[0], nullptr, resid, resmask, g, beta, C, r0,      lane);
  ln_ep(acc[1], nullptr, resid, resmask, g, beta, C, r0 + 16, lane);
}

// induced attention via MFMA; St2 bf16.
__global__ __launch_bounds__(512) void attn_pv(const unsigned short* __restrict__ St2,
    const unsigned short* __restrict__ V, float* __restrict__ O){
  __shared__ __align__(16) unsigned short Vt[2][4096];
  __shared__ __align__(16) float Ocomb[4][64][4];
  __shared__ float scomb[4][16];
  int b = blockIdx.x >> 2, h = blockIdx.x & 3;
  int lane = threadIdx.x & 63, w = threadIdx.x >> 6;
  int li = lane & 15, lg = lane >> 4;
  int qh = w & 1, dh = (w >> 1) & 1, jh = w >> 2;
  int tq = w & 3;
  const unsigned short* Sp = St2 + ((size_t)(b*128 + h*32 + qh*16 + li)) * 2048 + jh*1024;
  const unsigned short* Vb = V + (size_t)b*NN*128 + h*32;
  unsigned short* VtJ = Vt[jh];
  int vrow = tq*32 + (lane >> 2);
  int vd0  = (lane & 3) * 8;
  const unsigned short* vsrc = Vb + ((size_t)(jh*1024 + vrow))*128 + vd0;

  f32x4 acc = (f32x4){0.f,0.f,0.f,0.f};
  float s = 0.f;
  bf16x8 Ar[2][4];
  bf16x8 vr[2][2];

  #pragma unroll
  for (int t = 0; t < 2; t++)
    vr[0][t] = *reinterpret_cast<const bf16x8*>(vsrc + (size_t)t*16*128);
  #pragma unroll
  for (int ks = 0; ks < 4; ks++)
    Ar[0][ks] = *reinterpret_cast<const bf16x8*>(Sp + ks*32 + lg*8);

  #pragma unroll
  for (int c = 0; c < 8; c++){
    const int cur = c & 1, nxt = cur ^ 1;
    __syncthreads();
    #pragma unroll
    for (int t = 0; t < 2; t++){
      int jl = vrow + t*16;
      #pragma unroll
      for (int e = 0; e < 8; e++){
        int d = vd0 + e;
        VtJ[(d << 7) + (jl ^ ((d & 7) << 3))] = (unsigned short)vr[cur][t][e];
      }
    }
    __syncthreads();
    if (c < 7){
      #pragma unroll
      for (int t = 0; t < 2; t++)
        vr[nxt][t] = *reinterpret_cast<const bf16x8*>(vsrc + ((size_t)(c+1)*128 + t*16)*128);
      #pragma unroll
      for (int ks = 0; ks < 4; ks++)
        Ar[nxt][ks] = *reinterpret_cast<const bf16x8*>(Sp + (c+1)*128 + ks*32 + lg*8);
    }
    #pragma unroll
    for (int ks = 0; ks < 4; ks++){
      bf16x8 a;
      #pragma unroll
      for (int e = 0; e < 8; e++){
        float pv = __expf(fminf(bf2f((unsigned short)Ar[cur][ks][e]), 60.f));
        s += pv; a[e] = (short)f2bf(pv);
      }
      bf16x8 bb = bfrag(VtJ, dh, ks*32, lane);
      acc = MFMA(a, bb, acc, 0, 0, 0);
    }
  }
  s += __shfl_xor(s, 16);
  s += __shfl_xor(s, 32);
  if (jh == 1){
    *reinterpret_cast<f32x4*>(&Ocomb[tq][lane][0]) = acc;
    if (lg == 0) scomb[tq][li] = s;
  }
  __syncthreads();
  if (jh == 0){
    acc += *reinterpret_cast<const f32x4*>(&Ocomb[tq][lane][0]);
    float inv = 1.f / (s + scomb[tq][li]);
    float* op = O + ((size_t)(b*MM + qh*16))*128 + h*32 + dh*16 + li;
    #pragma unroll
    for (int r = 0; r < 4; r++){
      float iv = __shfl(inv, lg*4 + r);
      op[(size_t)(lg*4 + r)*128] = acc[r] * iv;
    }
  }
}

// phase-B fused attention, operand-swapped; 512t / 256 rows / 64KB LDS.
template<typename TX>
__global__ __launch_bounds__(512, 2) void attn_swp(const TX* __restrict__ X,
    const unsigned short* __restrict__ WfImgs, const unsigned short* __restrict__ GvImgs,
    const float* __restrict__ g, const float* __restrict__ beta,
    unsigned short* __restrict__ X1){
  __shared__ __align__(16) unsigned short WtF[16384];
  __shared__ __align__(16) unsigned short WtG[16384];
  int b = blockIdx.x >> 3;            // 8 blocks per batch (256 rows each)
  stage_img<8>(WfImgs + (size_t)b*16384, WtF);
  stage_img<8>(GvImgs + (size_t)b*16384, WtG);
  int lane = threadIdx.x & 63, wave = threadIdx.x >> 6;
  int li = lane & 15, lg = lane >> 4;
  int r0 = blockIdx.x*256 + wave*32;
  bf16x8 af[2][4];
  load_afrag(X, r0, lane, af);
  __syncthreads();
  f32x4 sv[2][8];
  zero_acc(sv);
  mfma_swp(af, WtF, lane, sv);        // sv[s][cb][q] = S[row=s*16+li][kp=16cb+4lg+q]
  u32 pk[2][8][2];
  #pragma unroll
  for (int s = 0; s < 2; s++)
    #pragma unroll
    for (int h = 0; h < 4; h++){
      float p[8];
      #pragma unroll
      for (int q = 0; q < 4; q++){ p[q] = sv[s][2*h][q]; p[4+q] = sv[s][2*h+1][q]; }
      float m = fmaxf(fmaxf(fmaxf(p[0],p[1]),fmaxf(p[2],p[3])),
                      fmaxf(fmaxf(p[4],p[5]),fmaxf(p[6],p[7])));
      m = fmaxf(m, __shfl_xor(m, 16));
      m = fmaxf(m, __shfl_xor(m, 32));
      float sm = 0.f;
      #pragma unroll
      for (int i = 0; i < 8; i++){ p[i] = __expf(p[i] - m); sm += p[i]; }
      sm += __shfl_xor(sm, 16);
      sm += __shfl_xor(sm, 32);
      float inv = 1.f / sm;
      pk[s][2*h][0]   = pack2(p[0]*inv, p[1]*inv);
      pk[s][2*h][1]   = pack2(p[2]*inv, p[3]*inv);
      pk[s][2*h+1][0] = pack2(p[4]*inv, p[5]*inv);
      pk[s][2*h+1][1] = pack2(p[6]*inv, p[7]*inv);
    }
  int t = lg >> 1;
  int srcA = li + (((lane >> 4) & 1) << 5);
  int srcB = srcA + 16;
  f32x4 accO[2][8];
  zero_acc(accO);
  #pragma unroll
  for (int ks = 0; ks < 4; ks++){
    bf16x8 hb0 = redist(pk, 0, ks, t, srcA, srcB);
    bf16x8 hb1 = redist(pk, 1, ks, t, srcA, srcB);
    #pragma unroll
    for (int cb = 0; cb < 8; cb++){
      bf16x8 w = bfrag(WtG, cb, ks*32, lane);
      accO[0][cb] = MFMA(w, hb0, accO[0][cb], 0, 0, 0);
      accO[1][cb] = MFMA(w, hb1, accO[1][cb], 0, 0, 0);
    }
  }
  ln_swp(accO, nullptr, X, g, beta, X1, r0, lane);
}

// fused FFN, operand-swapped; 512t / 256 rows / 128KB dynamic LDS with ping-pong
// W1/W2 buffers: ONE barrier per dc (5 total vs 9). Registers (not LDS) gate
// occupancy at ~1 block/CU, so the extra LDS is free.
template<typename TA, typename TO>
__global__ __launch_bounds__(512, 2) void ffn_swp(const TA* __restrict__ X,
    const unsigned short* __restrict__ W1i, const float* __restrict__ b1,
    const unsigned short* __restrict__ W2i, const float* __restrict__ b2,
    const float* __restrict__ g, const float* __restrict__ beta,
    TO* __restrict__ OUT){
  extern __shared__ __align__(16) unsigned short sm[];
  // layout: W1 bufs at 0 / 16384; W2 bufs at 32768 / 49152
  int lane = threadIdx.x & 63, wave = threadIdx.x >> 6;
  int li = lane & 15, lg = lane >> 4;
  int r0 = blockIdx.x*256 + wave*32;
  bf16x8 af[2][4];
  load_afrag(X, r0, lane, af);
  f32x4 accO[2][8];
  zero_acc(accO);
  stage_img<8>(W1i, sm);
  stage_img<8>(W2i, sm + 32768);
  __syncthreads();
  int t = lg >> 1;
  int srcA = li + (((lane >> 4) & 1) << 5);
  int srcB = srcA + 16;
  for (int dc = 0; dc < 4; dc++){
    int cur = dc & 1;
    const unsigned short* W1c = sm + cur*16384;
    const unsigned short* W2c = sm + 32768 + cur*16384;
    if (dc < 3){                        // prefetch next dc into idle buffers
      stage_img<8>(W1i + (dc+1)*16384, sm + (cur^1)*16384);
      stage_img<8>(W2i + (dc+1)*16384, sm + 32768 + (cur^1)*16384);
    }
    f32x4 acc1[2][8];
    zero_acc(acc1);
    mfma_swp(af, W1c, lane, acc1);
    u32 pk[2][8][2];
    #pragma unroll
    for (int s = 0; s < 2; s++)
      #pragma unroll
      for (int cb = 0; cb < 8; cb++){
        f32x4 bq = *reinterpret_cast<const f32x4*>(b1 + dc*128 + cb*16 + lg*4);
        float v0 = fmaxf(acc1[s][cb][0] + bq[0], 0.f);
        float v1 = fmaxf(acc1[s][cb][1] + bq[1], 0.f);
        float v2 = fmaxf(acc1[s][cb][2] + bq[2], 0.f);
        float v3 = fmaxf(acc1[s][cb][3] + bq[3], 0.f);
        pk[s][cb][0] = pack2(v0, v1);
        pk[s][cb][1] = pack2(v2, v3);
      }
    #pragma unroll
    for (int ks = 0; ks < 4; ks++){
      bf16x8 hb0 = redist(pk, 0, ks, t, srcA, srcB);
      bf16x8 hb1 = redist(pk, 1, ks, t, srcA, srcB);
      #pragma unroll
      for (int cb = 0; cb < 8; cb++){
        bf16x8 w = bfrag(W2c, cb, ks*32, lane);
        accO[0][cb] = MFMA(w, hb0, accO[0][cb], 0, 0, 0);
        accO[1][cb] = MFMA(w, hb1, accO[1][cb], 0, 0, 0);
      }
    }
    __syncthreads();   // next-dc stages drained; current-buffer reads done (safe to overwrite at dc+2)
  }
  ln_swp(accO, b2, X, g, beta, OUT, r0, lane);
}

extern "C" void kernel_launch(void* const* d_in, const int* in_sizes, int n_in,
                              void* d_out, int out_size, void* d_ws, size_t ws_size,
                              hipStream_t stream){
  (void)in_sizes; (void)n_in; (void)out_size;
  const float* feat = (const float*)d_in[0];
  const float* Ipts = (const float*)d_in[1];
  const float* Wq   = (const float*)d_in[2];
  const float* Wk   = (const float*)d_in[3];
  const float* Wv   = (const float*)d_in[4];
  const float* Wo   = (const float*)d_in[5];
  const float* W1   = (const float*)d_in[6];
  const float* b1   = (const float*)d_in[7];
  const float* W2   = (const float*)d_in[8];
  const float* b2   = (const float*)d_in[9];
  const float* g1   = (const float*)d_in[10];
  const float* be1  = (const float*)d_in[11];
  const float* g2   = (const float*)d_in[12];
  const float* be2  = (const float*)d_in[13];
  float* out = (float*)d_out;

  unsigned short* St2  = (unsigned short*)d_ws;        // 32MB bf16 scores(T); aliased by bigX1
  unsigned short* bigX1 = St2;                          // phase-B attn out (St2 dead by then)
  unsigned short* bigV = St2 + (size_t)BN*128;         // 32MB bf16 V
  float* Oind  = (float*)(bigV + (size_t)BN*128);
  float* x1ind = Oind  + (size_t)BM*128;
  float* Hind  = x1ind + (size_t)BM*128;
  float* Khb   = Hind  + (size_t)BM*128;
  float* Vhb   = Khb   + (size_t)BM*128;
  unsigned short* imgs = (unsigned short*)(Vhb + (size_t)BM*128);

  unsigned short* imgQKVO = imgs;
  unsigned short* imgW1   = imgs + (size_t)16*16384;
  unsigned short* imgW2   = imgs + (size_t)32*16384;
  unsigned short* imgWf   = imgs + (size_t)48*16384;
  unsigned short* wfB     = imgs + (size_t)50*16384;
  unsigned short* gvB     = imgs + (size_t)114*16384;
  unsigned short* xb      = imgs + (size_t)178*16384;  // 32MB bf16 x (all layers, optional)
  size_t need = (size_t)((char*)(xb + (size_t)BN*128) - (char*)d_ws);
  bool useXb = (ws_size >= need);

  prep_imgs<<<48, 256, 0, stream>>>(Wq, Wk, Wv, Wo, W1, W2, imgs);
  if (useXb)
    cvt_bf16<<<BN*128/8/256, 256, 0, stream>>>(feat, xb);   // bf16 x for layer 0

  for (int l = 0; l < LL; l++){
    const float* xf = (l == 0) ? feat : out;
    bool xBf = useXb;
    const float* Il = Ipts + l*MM*DD;
    int j0 = l*2, j1 = l*2 + 1;
    // ---- phase A: H = MAB(I, x) ----
    prep_phaseA<<<16, 256, 0, stream>>>(Il, Wq + j0*16384, Wk + j0*16384, imgWf + l*16384);
    if (xBf)
      gemm_dual<unsigned short><<<BN/256, 512, 0, stream>>>(xb, imgWf + l*16384,
          imgQKVO + (j0*4+2)*16384, St2, bigV);
    else
      gemm_dual<float><<<BN/256, 512, 0, stream>>>(xf, imgWf + l*16384,
          imgQKVO + (j0*4+2)*16384, St2, bigV);
    attn_pv<<<BB*HH, 512, 0, stream>>>(St2, bigV, Oind);
    gemm_ln_f32A<<<BM/128, 256, 0, stream>>>(Oind, imgQKVO + (j0*4+3)*16384, Il, 31u,
                                             g1 + j0*128, be1 + j0*128, x1ind);
    ffn_swp<float, float><<<BM/256, 512, 131072, stream>>>(x1ind, imgW1 + (size_t)j0*4*16384,
        b1 + j0*512, imgW2 + (size_t)j0*4*16384, b2 + j0*128,
        g2 + j0*128, be2 + j0*128, Hind);
    // ---- phase B: x = MAB(x, H) ----
    gemm_img<<<BM/128, 256, 0, stream>>>(Hind, imgQKVO + (j1*4+1)*16384, Khb);
    gemm_img<<<BM/128, 256, 0, stream>>>(Hind, imgQKVO + (j1*4+2)*16384, Vhb);
    prep_phaseB<<<BB*8, 256, 0, stream>>>(Wq + j1*16384, Wo + j1*16384, Khb, Vhb, wfB, gvB);
    if (xBf)
      attn_swp<unsigned short><<<BN/256, 512, 0, stream>>>(xb, wfB, gvB,
          g1 + j1*128, be1 + j1*128, bigX1);
    else
      attn_swp<float><<<BN/256, 512, 0, stream>>>(xf, wfB, gvB,
          g1 + j1*128, be1 + j1*128, bigX1);
    if (l == 0 && useXb)
      ffn_swp<unsigned short, unsigned short><<<BN/256, 512, 131072, stream>>>(bigX1,
          imgW1 + (size_t)j1*4*16384, b1 + j1*512, imgW2 + (size_t)j1*4*16384, b2 + j1*128,
          g2 + j1*128, be2 + j1*128, xb);
    else
      ffn_swp<unsigned short, float><<<BN/256, 512, 131072, stream>>>(bigX1,
          imgW1 + (size_t)j1*4*16384, b1 + j1*512, imgW2 + (size_t)j1*4*16384, b2 + j1*128,
          g2 + j1*128, be2 + j1*128, out);
  }
}